// Round 6
// baseline (814.010 us; speedup 1.0000x reference)
//
#include <hip/hip_runtime.h>
#include <math.h>

// Problem constants (fixed shape)
#define B 256
#define W 512
#define F 512
#define N 512
#define GP 2               // blocks per sample
#define NBLK (B * GP)      // 512 blocks = 2 per CU (resources allow 4 -> safe)
#define WPB (W / GP)       // 256 words per block

// ---------------------------------------------------------------------------
// Device-scope generation barrier.  cnt/gen live in d_ws, zeroed by init
// kernel before the main kernel each launch.  All NBLK blocks call it the
// same number of times.
// ---------------------------------------------------------------------------
__device__ inline void grid_barrier(unsigned* cnt, unsigned* gen) {
    __syncthreads();
    if (threadIdx.x == 0) {
        __threadfence();   // make prior global writes device-visible
        unsigned g = __hip_atomic_load(gen, __ATOMIC_RELAXED, __HIP_MEMORY_SCOPE_AGENT);
        unsigned arrived = __hip_atomic_fetch_add(cnt, 1u, __ATOMIC_ACQ_REL, __HIP_MEMORY_SCOPE_AGENT);
        if (arrived == NBLK - 1) {
            __hip_atomic_store(cnt, 0u, __ATOMIC_RELAXED, __HIP_MEMORY_SCOPE_AGENT);
            __hip_atomic_store(gen, g + 1u, __ATOMIC_RELEASE, __HIP_MEMORY_SCOPE_AGENT);
        } else {
            while (__hip_atomic_load(gen, __ATOMIC_ACQUIRE, __HIP_MEMORY_SCOPE_AGENT) == g) {
                __builtin_amdgcn_s_sleep(2);
            }
        }
        __threadfence();
    }
    __syncthreads();
}

__global__ void init_barrier(unsigned* bar) {
    bar[0] = 0u;   // cnt
    bar[1] = 0u;   // gen
}

// ---------------------------------------------------------------------------
// Fused persistent kernel.  Block (b,g): b = blk>>1, g = blk&1, owns words
// [g*256, g*256+256) of sample b.  256 threads (4 waves).
// ---------------------------------------------------------------------------
__global__ __launch_bounds__(256, 4) void fused_kernel(
    const float* __restrict__ x,
    const float* __restrict__ Wk,
    const float* __restrict__ Wq,
    const float* __restrict__ Wv,
    const float* __restrict__ wvec,
    unsigned*    __restrict__ bar,      // [cnt, gen]
    float* __restrict__ t_part,         // NBLK*F
    float* __restrict__ Qbuf,           // B*N
    float* __restrict__ rbuf,           // B*F
    float* __restrict__ c_part,         // NBLK*F
    float* __restrict__ ml_part,        // NBLK*2
    float* __restrict__ out)            // B*N
{
    const int blk = blockIdx.x;
    const int g   = blk & (GP - 1);
    const int b   = blk >> 1;
    const int tid = threadIdx.x;

    __shared__ float smem[2056];   // union across phases (8.25 KB)

    unsigned* cnt = bar;
    unsigned* gen = bar + 1;

    // ---------------- Phase 1: t partial over this block's 256 words --------
    {
        float* s_w    = smem;          // 256
        float* s_part = smem + 256;    // 2*512
        s_w[tid] = wvec[g * WPB + tid];
        __syncthreads();

        const int half = tid >> 7;     // 0..1 -> 128 words each
        const int f4   = tid & 127;
        const float* xb = x + (size_t)b * W * F + (size_t)(g * WPB + half * 128) * F;

        float4 acc = make_float4(0.f, 0.f, 0.f, 0.f);
        for (int c = 0; c < 16; ++c) {
            float wr[8];
#pragma unroll
            for (int j = 0; j < 8; ++j) wr[j] = s_w[half * 128 + c * 8 + j];
            float4 xv[8];
#pragma unroll
            for (int j = 0; j < 8; ++j)
                xv[j] = *(const float4*)(xb + (size_t)(c * 8 + j) * F + f4 * 4);
#pragma unroll
            for (int j = 0; j < 8; ++j) {
                acc.x += xv[j].x * wr[j]; acc.y += xv[j].y * wr[j];
                acc.z += xv[j].z * wr[j]; acc.w += xv[j].w * wr[j];
            }
        }
        *(float4*)&s_part[half * 512 + f4 * 4] = acc;
        __syncthreads();

        t_part[(size_t)blk * F + tid]       = s_part[tid]       + s_part[512 + tid];
        t_part[(size_t)blk * F + tid + 256] = s_part[tid + 256] + s_part[768 + tid];
    }
    grid_barrier(cnt, gen);

    // ---------------- Phase 2: Q slice (n in [g*256, g*256+256)) ------------
    {
        float* s_t = smem;   // 512
        const float* tp0 = t_part + ((size_t)b * GP + 0) * F;
        const float* tp1 = t_part + ((size_t)b * GP + 1) * F;
        s_t[tid]       = tp0[tid]       + tp1[tid];
        s_t[tid + 256] = tp0[tid + 256] + tp1[tid + 256];
        __syncthreads();

        const float* wqc = Wq + g * 256 + tid;     // column n
        float qa[8] = {0.f,0.f,0.f,0.f,0.f,0.f,0.f,0.f};
        for (int f = 0; f < F; f += 8) {
#pragma unroll
            for (int j = 0; j < 8; ++j)
                qa[j] += s_t[f + j] * wqc[(size_t)(f + j) * N];
        }
        Qbuf[(size_t)b * N + g * 256 + tid] =
            ((qa[0]+qa[1])+(qa[2]+qa[3])) + ((qa[4]+qa[5])+(qa[6]+qa[7]));
    }
    grid_barrier(cnt, gen);

    // ---------------- Phase 3: r slice (f in [g*256, g*256+256)) ------------
    {
        float* s_q = smem;   // 512
        s_q[tid]       = Qbuf[(size_t)b * N + tid];
        s_q[tid + 256] = Qbuf[(size_t)b * N + tid + 256];
        __syncthreads();

        const int ff = g * 256 + tid;
        const float4* krow = (const float4*)(Wk + (size_t)ff * N);
        const float4* qv4  = (const float4*)s_q;
        float ra[4] = {0.f, 0.f, 0.f, 0.f};
#pragma unroll 8
        for (int n4 = 0; n4 < N / 4; ++n4) {
            const float4 kv = krow[n4];
            const float4 qv = qv4[n4];
            ra[0] += kv.x * qv.x; ra[1] += kv.y * qv.y;
            ra[2] += kv.z * qv.z; ra[3] += kv.w * qv.w;
        }
        rbuf[(size_t)b * F + ff] =
            ((ra[0] + ra[1]) + (ra[2] + ra[3])) * 0.04419417382415922f; // 1/sqrt(512)
    }
    grid_barrier(cnt, gen);

    // ---------------- Phase 4: attn partial over this block's 256 words -----
    {
        float* s_c = smem;          // 4*512
        float* s_m = smem + 2048;   // 4
        float* s_l = smem + 2052;   // 4
        const int lane = tid & 63;
        const int wv   = tid >> 6;  // 0..3, 64 words each

        const float* xb = x + (size_t)b * W * F;
        const float* rb = rbuf + (size_t)b * F;
        const float4 r0 = *(const float4*)(rb + lane * 4);
        const float4 r1 = *(const float4*)(rb + 256 + lane * 4);

        // two independent online-softmax streams (ILP), flash-merged at end
        float m0 = -INFINITY, l0 = 0.f, m1 = -INFINITY, l1 = 0.f;
        float4 cA0 = make_float4(0.f,0.f,0.f,0.f), cA1 = make_float4(0.f,0.f,0.f,0.f);
        float4 cB0 = make_float4(0.f,0.f,0.f,0.f), cB1 = make_float4(0.f,0.f,0.f,0.f);

        const int wbase = g * WPB + wv * 64;
        for (int i = 0; i < 64; i += 4) {
            const float* rA = xb + (size_t)(wbase + i) * F;
            const float* rB = rA + F;
            const float* rC = rB + F;
            const float* rD = rC + F;
            const float4 a0 = *(const float4*)(rA + lane * 4);
            const float4 a1 = *(const float4*)(rA + 256 + lane * 4);
            const float4 b0 = *(const float4*)(rB + lane * 4);
            const float4 b1 = *(const float4*)(rB + 256 + lane * 4);
            const float4 e0 = *(const float4*)(rC + lane * 4);
            const float4 e1 = *(const float4*)(rC + 256 + lane * 4);
            const float4 f0 = *(const float4*)(rD + lane * 4);
            const float4 f1 = *(const float4*)(rD + 256 + lane * 4);

            float dA = a0.x*r0.x + a0.y*r0.y + a0.z*r0.z + a0.w*r0.w
                     + a1.x*r1.x + a1.y*r1.y + a1.z*r1.z + a1.w*r1.w;
            float dB = b0.x*r0.x + b0.y*r0.y + b0.z*r0.z + b0.w*r0.w
                     + b1.x*r1.x + b1.y*r1.y + b1.z*r1.z + b1.w*r1.w;
            float dC = e0.x*r0.x + e0.y*r0.y + e0.z*r0.z + e0.w*r0.w
                     + e1.x*r1.x + e1.y*r1.y + e1.z*r1.z + e1.w*r1.w;
            float dD = f0.x*r0.x + f0.y*r0.y + f0.z*r0.z + f0.w*r0.w
                     + f1.x*r1.x + f1.y*r1.y + f1.z*r1.z + f1.w*r1.w;
#pragma unroll
            for (int off = 32; off >= 1; off >>= 1) {
                dA += __shfl_xor(dA, off, 64);
                dB += __shfl_xor(dB, off, 64);
                dC += __shfl_xor(dC, off, 64);
                dD += __shfl_xor(dD, off, 64);
            }

            // stream 0: A then B
            {
                float mn = fmaxf(m0, dA);
                float sc = __expf(m0 - mn);
                float p  = __expf(dA - mn);
                l0 = l0 * sc + p;
                cA0.x = cA0.x*sc + p*a0.x; cA0.y = cA0.y*sc + p*a0.y;
                cA0.z = cA0.z*sc + p*a0.z; cA0.w = cA0.w*sc + p*a0.w;
                cA1.x = cA1.x*sc + p*a1.x; cA1.y = cA1.y*sc + p*a1.y;
                cA1.z = cA1.z*sc + p*a1.z; cA1.w = cA1.w*sc + p*a1.w;
                m0 = mn;
                mn = fmaxf(m0, dB);
                sc = __expf(m0 - mn);
                p  = __expf(dB - mn);
                l0 = l0 * sc + p;
                cA0.x = cA0.x*sc + p*b0.x; cA0.y = cA0.y*sc + p*b0.y;
                cA0.z = cA0.z*sc + p*b0.z; cA0.w = cA0.w*sc + p*b0.w;
                cA1.x = cA1.x*sc + p*b1.x; cA1.y = cA1.y*sc + p*b1.y;
                cA1.z = cA1.z*sc + p*b1.z; cA1.w = cA1.w*sc + p*b1.w;
                m0 = mn;
            }
            // stream 1: C then D
            {
                float mn = fmaxf(m1, dC);
                float sc = __expf(m1 - mn);
                float p  = __expf(dC - mn);
                l1 = l1 * sc + p;
                cB0.x = cB0.x*sc + p*e0.x; cB0.y = cB0.y*sc + p*e0.y;
                cB0.z = cB0.z*sc + p*e0.z; cB0.w = cB0.w*sc + p*e0.w;
                cB1.x = cB1.x*sc + p*e1.x; cB1.y = cB1.y*sc + p*e1.y;
                cB1.z = cB1.z*sc + p*e1.z; cB1.w = cB1.w*sc + p*e1.w;
                m1 = mn;
                mn = fmaxf(m1, dD);
                sc = __expf(m1 - mn);
                p  = __expf(dD - mn);
                l1 = l1 * sc + p;
                cB0.x = cB0.x*sc + p*f0.x; cB0.y = cB0.y*sc + p*f0.y;
                cB0.z = cB0.z*sc + p*f0.z; cB0.w = cB0.w*sc + p*f0.w;
                cB1.x = cB1.x*sc + p*f1.x; cB1.y = cB1.y*sc + p*f1.y;
                cB1.z = cB1.z*sc + p*f1.z; cB1.w = cB1.w*sc + p*f1.w;
                m1 = mn;
            }
        }

        // merge the two streams (wave-uniform)
        const float Mw = fmaxf(m0, m1);
        const float s0 = __expf(m0 - Mw);
        const float s1 = __expf(m1 - Mw);
        const float Lw = s0 * l0 + s1 * l1;
        float4 w0, w1;
        w0.x = s0*cA0.x + s1*cB0.x; w0.y = s0*cA0.y + s1*cB0.y;
        w0.z = s0*cA0.z + s1*cB0.z; w0.w = s0*cA0.w + s1*cB0.w;
        w1.x = s0*cA1.x + s1*cB1.x; w1.y = s0*cA1.y + s1*cB1.y;
        w1.z = s0*cA1.z + s1*cB1.z; w1.w = s0*cA1.w + s1*cB1.w;

        *(float4*)&s_c[wv * 512 + lane * 4]       = w0;
        *(float4*)&s_c[wv * 512 + 256 + lane * 4] = w1;
        if (lane == 0) { s_m[wv] = Mw; s_l[wv] = Lw; }
        __syncthreads();

        const float M = fmaxf(fmaxf(s_m[0], s_m[1]), fmaxf(s_m[2], s_m[3]));
        const float a0w = __expf(s_m[0] - M), a1w = __expf(s_m[1] - M);
        const float a2w = __expf(s_m[2] - M), a3w = __expf(s_m[3] - M);
        const float L = a0w*s_l[0] + a1w*s_l[1] + a2w*s_l[2] + a3w*s_l[3];

#pragma unroll
        for (int k = 0; k < 2; ++k) {
            const int f = tid + k * 256;
            c_part[(size_t)blk * F + f] =
                a0w*s_c[f] + a1w*s_c[512+f] + a2w*s_c[1024+f] + a3w*s_c[1536+f];
        }
        if (tid == 0) { ml_part[blk * 2] = M; ml_part[blk * 2 + 1] = L; }
    }
    grid_barrier(cnt, gen);

    // ---------------- Phase 5: flash-merge + Wv projection (n slice) --------
    {
        float* s_cf = smem;   // 512
        const float M0 = ml_part[(b * GP + 0) * 2];
        const float M1 = ml_part[(b * GP + 1) * 2];
        const float M  = fmaxf(M0, M1);
        const float a0 = __expf(M0 - M);
        const float a1 = __expf(M1 - M);
        const float L  = a0 * ml_part[(b * GP + 0) * 2 + 1]
                       + a1 * ml_part[(b * GP + 1) * 2 + 1];
        const float invL = 1.f / L;

        const float* cp0 = c_part + ((size_t)b * GP + 0) * F;
        const float* cp1 = c_part + ((size_t)b * GP + 1) * F;
        s_cf[tid]       = (a0 * cp0[tid]       + a1 * cp1[tid])       * invL;
        s_cf[tid + 256] = (a0 * cp0[tid + 256] + a1 * cp1[tid + 256]) * invL;
        __syncthreads();

        const float* wvc = Wv + g * 256 + tid;   // column n
        float oa[8] = {0.f,0.f,0.f,0.f,0.f,0.f,0.f,0.f};
        for (int f = 0; f < F; f += 8) {
#pragma unroll
            for (int j = 0; j < 8; ++j)
                oa[j] += s_cf[f + j] * wvc[(size_t)(f + j) * N];
        }
        out[(size_t)b * N + g * 256 + tid] =
            ((oa[0]+oa[1])+(oa[2]+oa[3])) + ((oa[4]+oa[5])+(oa[6]+oa[7]));
    }
}

// ---------------------------------------------------------------------------
// Launcher.  ws layout: 64 uints barrier | t_part NBLK*F | Qbuf B*N |
// rbuf B*F | c_part NBLK*F | ml_part NBLK*2   (~3.1 MB of the 1 GB ws)
// ---------------------------------------------------------------------------
extern "C" void kernel_launch(void* const* d_in, const int* in_sizes, int n_in,
                              void* d_out, int out_size, void* d_ws, size_t ws_size,
                              hipStream_t stream)
{
    const float* x    = (const float*)d_in[0];
    const float* Wk   = (const float*)d_in[1];
    const float* Wq   = (const float*)d_in[2];
    const float* Wv   = (const float*)d_in[3];
    const float* wvec = (const float*)d_in[4];
    float* out = (float*)d_out;

    unsigned* bar  = (unsigned*)d_ws;
    float* t_part  = (float*)d_ws + 64;
    float* Qbuf    = t_part + (size_t)NBLK * F;
    float* rbuf    = Qbuf + (size_t)B * N;
    float* c_part  = rbuf + (size_t)B * F;
    float* ml_part = c_part + (size_t)NBLK * F;

    init_barrier<<<1, 1, 0, stream>>>(bar);
    fused_kernel<<<NBLK, 256, 0, stream>>>(x, Wk, Wq, Wv, wvec, bar,
                                           t_part, Qbuf, rbuf, c_part, ml_part, out);
}

// Round 7
// 755.940 us; speedup vs baseline: 1.0768x; 1.0768x over previous
//
#include <hip/hip_runtime.h>
#include <math.h>

// Problem constants (fixed shape)
#define B 256
#define W 512
#define F 512
#define N 512
#define GP 8             // partial blocks per sample for f-major x passes
#define WPB (W / GP)     // 64 words per partial block

// -----------------------------------------------------------------------------
// Kernel A: t partials.  grid = B*GP = 2048, 256 thr (8 blocks/CU -> 32 waves).
// Block (b,g) words [g*64, g*64+64); half = tid>>7 covers 32 words; f4 = tid&127
// covers the row in float4.  Loads batched 8-deep for MLP.
// -----------------------------------------------------------------------------
__global__ __launch_bounds__(256) void tpart_kernel(
    const float* __restrict__ x,
    const float* __restrict__ wvec,
    float* __restrict__ t_part)
{
    const int blk  = blockIdx.x;
    const int g    = blk & (GP - 1);
    const int b    = blk >> 3;
    const int tid  = threadIdx.x;
    const int half = tid >> 7;
    const int f4   = tid & 127;

    __shared__ float s_w[WPB];
    __shared__ float s_part[2][F];

    if (tid < WPB) s_w[tid] = wvec[g * WPB + tid];
    __syncthreads();

    const float* xb = x + (size_t)b * W * F + (size_t)(g * WPB + half * 32) * F;
    float4 acc = make_float4(0.f, 0.f, 0.f, 0.f);
    for (int c = 0; c < 4; ++c) {
        float wr[8];
#pragma unroll
        for (int j = 0; j < 8; ++j) wr[j] = s_w[half * 32 + c * 8 + j];
        float4 xv[8];
#pragma unroll
        for (int j = 0; j < 8; ++j)
            xv[j] = *(const float4*)(xb + (size_t)(c * 8 + j) * F + f4 * 4);
#pragma unroll
        for (int j = 0; j < 8; ++j) {
            acc.x += xv[j].x * wr[j]; acc.y += xv[j].y * wr[j];
            acc.z += xv[j].z * wr[j]; acc.w += xv[j].w * wr[j];
        }
    }
    *(float4*)&s_part[half][f4 * 4] = acc;
    __syncthreads();

    t_part[(size_t)blk * F + tid]       = s_part[0][tid]       + s_part[1][tid];
    t_part[(size_t)blk * F + tid + 256] = s_part[0][tid + 256] + s_part[1][tid + 256];
}

// -----------------------------------------------------------------------------
// Kernel B: reduce t partials, Q = t@Wq, r = (1/sqrt(N)) * Wk@Q.
// grid = B, 512 threads.  Weights are L2-resident (1 MB each).
// -----------------------------------------------------------------------------
__global__ __launch_bounds__(512) void qr_kernel(
    const float* __restrict__ t_part,
    const float* __restrict__ Wq,
    const float* __restrict__ Wk,
    float* __restrict__ r_out)
{
    __shared__ float s_t[F];
    __shared__ float s_q[N];
    const int b = blockIdx.x, tid = threadIdx.x;

    float t = 0.f;
#pragma unroll
    for (int g = 0; g < GP; ++g)
        t += t_part[((size_t)b * GP + g) * F + tid];
    s_t[tid] = t;
    __syncthreads();

    float qa[8] = {0.f, 0.f, 0.f, 0.f, 0.f, 0.f, 0.f, 0.f};
#pragma unroll 4
    for (int f = 0; f < F; f += 8) {
#pragma unroll
        for (int j = 0; j < 8; ++j)
            qa[j] += s_t[f + j] * Wq[(size_t)(f + j) * N + tid];
    }
    s_q[tid] = ((qa[0] + qa[1]) + (qa[2] + qa[3]))
             + ((qa[4] + qa[5]) + (qa[6] + qa[7]));
    __syncthreads();

    const float4* wkrow = (const float4*)(Wk + (size_t)tid * N);
    float r0 = 0.f, r1 = 0.f, r2 = 0.f, r3 = 0.f;
#pragma unroll 8
    for (int n4 = 0; n4 < N / 4; ++n4) {
        const float4 kv = wkrow[n4];
        const float4 qv = *(const float4*)&s_q[n4 * 4];
        r0 += kv.x * qv.x; r1 += kv.y * qv.y;
        r2 += kv.z * qv.z; r3 += kv.w * qv.w;
    }
    r_out[(size_t)b * F + tid] =
        ((r0 + r1) + (r2 + r3)) * 0.04419417382415922f;  // 1/sqrt(512)
}

// -----------------------------------------------------------------------------
// Kernel C: scores + softmax.  grid = B, 512 threads; thread tid owns word tid.
// Private dot (8 independent float4 streams, NO cross-lane reduce), then
// block softmax over the 512 scores -> normalized p[b,w].
// -----------------------------------------------------------------------------
__global__ __launch_bounds__(512) void score_kernel(
    const float* __restrict__ x,
    const float* __restrict__ r_in,
    float* __restrict__ p_out)
{
    const int b = blockIdx.x, tid = threadIdx.x;
    const int lane = tid & 63, wv = tid >> 6;
    __shared__ float s_r[F];
    __shared__ float s_mred[8];
    __shared__ float s_lred[8];

    s_r[tid] = r_in[(size_t)b * F + tid];
    __syncthreads();

    const float* xrow = x + (size_t)b * W * F + (size_t)tid * F;
    float4 acc[8];
#pragma unroll
    for (int k = 0; k < 8; ++k) acc[k] = make_float4(0.f, 0.f, 0.f, 0.f);

    for (int i = 0; i < 16; ++i) {
        float4 xv[8];
#pragma unroll
        for (int k = 0; k < 8; ++k)
            xv[k] = *(const float4*)(xrow + k * 64 + i * 4);
#pragma unroll
        for (int k = 0; k < 8; ++k) {
            const float4 rv = *(const float4*)(&s_r[k * 64 + i * 4]);
            acc[k].x += xv[k].x * rv.x; acc[k].y += xv[k].y * rv.y;
            acc[k].z += xv[k].z * rv.z; acc[k].w += xv[k].w * rv.w;
        }
    }
    float4 a = acc[0];
#pragma unroll
    for (int k = 1; k < 8; ++k) {
        a.x += acc[k].x; a.y += acc[k].y; a.z += acc[k].z; a.w += acc[k].w;
    }
    const float s = (a.x + a.y) + (a.z + a.w);

    // block softmax over 512 scores
    float mv = s;
#pragma unroll
    for (int off = 32; off >= 1; off >>= 1)
        mv = fmaxf(mv, __shfl_xor(mv, off, 64));
    if (lane == 0) s_mred[wv] = mv;
    __syncthreads();
    float M = s_mred[0];
#pragma unroll
    for (int j = 1; j < 8; ++j) M = fmaxf(M, s_mred[j]);

    const float e = __expf(s - M);
    float ls = e;
#pragma unroll
    for (int off = 32; off >= 1; off >>= 1)
        ls += __shfl_xor(ls, off, 64);
    if (lane == 0) s_lred[wv] = ls;
    __syncthreads();
    float L = 0.f;
#pragma unroll
    for (int j = 0; j < 8; ++j) L += s_lred[j];

    p_out[(size_t)b * W + tid] = e / L;
}

// -----------------------------------------------------------------------------
// Kernel D: c partials (p-weighted sum of x over words).  Same structure as
// tpart but with p instead of wvec.  grid = B*GP, 256 threads.
// -----------------------------------------------------------------------------
__global__ __launch_bounds__(256) void cpart_kernel(
    const float* __restrict__ x,
    const float* __restrict__ p_in,
    float* __restrict__ c_part)
{
    const int blk  = blockIdx.x;
    const int g    = blk & (GP - 1);
    const int b    = blk >> 3;
    const int tid  = threadIdx.x;
    const int half = tid >> 7;
    const int f4   = tid & 127;

    __shared__ float s_p[WPB];
    __shared__ float s_part[2][F];

    if (tid < WPB) s_p[tid] = p_in[(size_t)b * W + g * WPB + tid];
    __syncthreads();

    const float* xb = x + (size_t)b * W * F + (size_t)(g * WPB + half * 32) * F;
    float4 acc = make_float4(0.f, 0.f, 0.f, 0.f);
    for (int c = 0; c < 4; ++c) {
        float pr[8];
#pragma unroll
        for (int j = 0; j < 8; ++j) pr[j] = s_p[half * 32 + c * 8 + j];
        float4 xv[8];
#pragma unroll
        for (int j = 0; j < 8; ++j)
            xv[j] = *(const float4*)(xb + (size_t)(c * 8 + j) * F + f4 * 4);
#pragma unroll
        for (int j = 0; j < 8; ++j) {
            acc.x += xv[j].x * pr[j]; acc.y += xv[j].y * pr[j];
            acc.z += xv[j].z * pr[j]; acc.w += xv[j].w * pr[j];
        }
    }
    *(float4*)&s_part[half][f4 * 4] = acc;
    __syncthreads();

    c_part[(size_t)blk * F + tid]       = s_part[0][tid]       + s_part[1][tid];
    c_part[(size_t)blk * F + tid + 256] = s_part[0][tid + 256] + s_part[1][tid + 256];
}

// -----------------------------------------------------------------------------
// Kernel E: sum c partials (already normalized), project through Wv.
// grid = B, 512 threads.
// -----------------------------------------------------------------------------
__global__ __launch_bounds__(512) void combine_kernel(
    const float* __restrict__ c_part,
    const float* __restrict__ Wv,
    float* __restrict__ out)
{
    __shared__ float s_cf[F];
    const int b = blockIdx.x, tid = threadIdx.x;

    float cf = 0.f;
#pragma unroll
    for (int g = 0; g < GP; ++g)
        cf += c_part[((size_t)b * GP + g) * F + tid];
    s_cf[tid] = cf;
    __syncthreads();

    float oa[8] = {0.f, 0.f, 0.f, 0.f, 0.f, 0.f, 0.f, 0.f};
#pragma unroll 4
    for (int f = 0; f < F; f += 8) {
#pragma unroll
        for (int j = 0; j < 8; ++j)
            oa[j] += s_cf[f + j] * Wv[(size_t)(f + j) * N + tid];
    }
    out[(size_t)b * N + tid] = ((oa[0] + oa[1]) + (oa[2] + oa[3]))
                             + ((oa[4] + oa[5]) + (oa[6] + oa[7]));
}

// -----------------------------------------------------------------------------
// Launcher.  ws layout (floats):
//   t_part B*GP*F (4 MB) | r B*F (512 KB) | p B*W (512 KB) | c_part B*GP*F (4 MB)
// -----------------------------------------------------------------------------
extern "C" void kernel_launch(void* const* d_in, const int* in_sizes, int n_in,
                              void* d_out, int out_size, void* d_ws, size_t ws_size,
                              hipStream_t stream)
{
    const float* x    = (const float*)d_in[0];
    const float* Wk   = (const float*)d_in[1];
    const float* Wq   = (const float*)d_in[2];
    const float* Wv   = (const float*)d_in[3];
    const float* wvec = (const float*)d_in[4];
    float* out    = (float*)d_out;
    float* t_part = (float*)d_ws;
    float* r      = t_part + (size_t)B * GP * F;
    float* p      = r + (size_t)B * F;
    float* c_part = p + (size_t)B * W;

    tpart_kernel<<<B * GP, 256, 0, stream>>>(x, wvec, t_part);
    qr_kernel<<<B, 512, 0, stream>>>(t_part, Wq, Wk, r);
    score_kernel<<<B, 512, 0, stream>>>(x, r, p);
    cpart_kernel<<<B * GP, 256, 0, stream>>>(x, p, c_part);
    combine_kernel<<<B, 512, 0, stream>>>(c_part, Wv, out);
}